// Round 3
// baseline (103.086 us; speedup 1.0000x reference)
//
#include <hip/hip_runtime.h>
#include <stdint.h>

// Pow2Quant: round each fp32 to the nearest entry of
// {-1,-.5,...,-0.0078125, 0, 0.0078125,...,1} with argmin-first-index
// tie-breaking (positive midpoints round toward smaller value, negative
// midpoints round toward larger magnitude; |x|==2^-8 -> 0 for positive,
// -2^-7 for negative).  Verified exact: round-2 absmax = 0.0.
typedef float __attribute__((ext_vector_type(4))) f32x4;

__device__ __forceinline__ float pow2_quant(float x) {
    uint32_t b    = __float_as_uint(x);
    uint32_t sign = b & 0x80000000u;
    uint32_t a    = b & 0x7FFFFFFFu;      // |x| bits (monotone as uint)
    uint32_t mant = a & 0x007FFFFFu;
    int e = (int)(a >> 23) - 127;

    // Round |x| to nearest power of two. Midpoint is mantissa 1.5 (0x400000).
    // positive: strict > (ties go down); negative: >= (ties go up in magnitude).
    bool up = sign ? (mant >= 0x00400000u) : (mant > 0x00400000u);
    int e2 = e + (up ? 1 : 0);

    // Clamp exponent into codebook range [-7, 0].
    int ec = e2 > 0 ? 0 : (e2 < -7 ? -7 : e2);
    uint32_t magbits = (uint32_t)(127 + ec) << 23;

    // Zero region: |x| <= 2^-8 (positive, tie -> 0) / |x| < 2^-8 (negative,
    // tie -> -2^-7). 2^-8 bits = 0x3B800000.
    bool zero = sign ? (a < 0x3B800000u) : (a <= 0x3B800000u);
    uint32_t res = (zero ? 0u : magbits) | sign;
    return __uint_as_float(res);
}

__device__ __forceinline__ f32x4 pow2_quant4(f32x4 v) {
    f32x4 r;
    r.x = pow2_quant(v.x);
    r.y = pow2_quant(v.y);
    r.z = pow2_quant(v.z);
    r.w = pow2_quant(v.w);
    return r;
}

// One thread handles float4 #i and #(i+half): two independent 16B nt-loads in
// flight per lane (ILP), both streams coalesced. Streaming data is marked
// non-temporal (no L2/L3 allocate; zero reuse).
__global__ void __launch_bounds__(256) pow2quant_kernel(const float* __restrict__ in,
                                                        float* __restrict__ out,
                                                        int n) {
    const int n4   = n >> 2;            // number of float4s
    const int half = (n4 + 1) >> 1;     // thread i covers {i, i+half}
    const f32x4* __restrict__ in4  = (const f32x4*)in;
    f32x4* __restrict__ out4 = (f32x4*)out;

    int i = blockIdx.x * blockDim.x + threadIdx.x;
    if (i < half) {
        f32x4 v0 = __builtin_nontemporal_load(in4 + i);
        const int j = i + half;
        const bool has2 = (j < n4);     // n4 even in this problem -> always true
        f32x4 v1 = {};
        if (has2) v1 = __builtin_nontemporal_load(in4 + j);

        f32x4 r0 = pow2_quant4(v0);
        __builtin_nontemporal_store(r0, out4 + i);
        if (has2) {
            f32x4 r1 = pow2_quant4(v1);
            __builtin_nontemporal_store(r1, out4 + j);
        }
    }

    // Scalar tail (n % 4). n = 16*256*56*56 is divisible by 4 -> dead here,
    // kept for generality.
    const int tail_start = n4 << 2;
    const int ti = blockIdx.x * blockDim.x + threadIdx.x;
    if (ti < n - tail_start) {
        out[tail_start + ti] = pow2_quant(in[tail_start + ti]);
    }
}

extern "C" void kernel_launch(void* const* d_in, const int* in_sizes, int n_in,
                              void* d_out, int out_size, void* d_ws, size_t ws_size,
                              hipStream_t stream) {
    const float* x = (const float*)d_in[0];
    // d_in[1] is the codebook; its values are compile-time constants of the
    // reference, folded into pow2_quant.
    float* out = (float*)d_out;
    const int n = in_sizes[0];

    const int n4   = n >> 2;
    const int half = (n4 + 1) >> 1;
    int blocks = (half + 255) / 256;    // exact cover, 2 float4/thread
    if (blocks < 1) blocks = 1;
    pow2quant_kernel<<<blocks, 256, 0, stream>>>(x, out, n);
}